// Round 10
// baseline (133.474 us; speedup 1.0000x reference)
//
#include <hip/hip_runtime.h>

// DotProductAttention reduced form (verified rounds 1-9, absmax 0.0156):
//   Qeff[q] = 0.7*Q[q-1] + Q[q] + 0.7*Q[q+1]  (zero pad at edges)
//   out[q]  = softmax_{k <= max(q-1,0)}( Qeff[q]·K[k]/8 + beta[k] ) @ V
// Round 10: attn was concurrency-starved (1 block/CU -> 2 waves/SIMD, ~85% stall).
// Now 512 blocks: block = (head, pair pr, q-half hf) covers rows [32hf..32hf+32)
// of BOTH q-tiles pr and 31-pr -> every block exactly 33 tile-units regardless of
// dispatcher pairing. 2 blocks/CU co-resident -> 4 waves/SIMD. Wave = kh x parity
// x qh (16 q-rows x 32 keys, every 2nd tile). V-frags + beta loaded inside comp
// (latency covered by QK+exp2); ka double-buffered distance-2. P packed by
// truncation. Frag store F[hd][tile][frag][lane][8] from cvt8 (unchanged).
// Permuted key->M-row keeps S^T C-frag == PV B-frag. Fixed-max softmax.

typedef short bf16x8 __attribute__((ext_vector_type(8)));
typedef float f32x4  __attribute__((ext_vector_type(4)));

constexpr int S_ = 2048;
constexpr int D_ = 64;
constexpr float LOG2E = 1.44269504088896341f;
constexpr float KSC = 0.125f * LOG2E;   // 1/sqrt(64), log2 domain

// pack two fp32 -> dword of 2 bf16 (round-half-up), lo in low 16
__device__ __forceinline__ unsigned pk2(float lo, float hi) {
    union { float f; unsigned u; } a, b;
    a.f = lo; b.f = hi;
    return __builtin_amdgcn_perm(b.u + 0x8000u, a.u + 0x8000u, 0x07060302u);
}
// truncating pack (P is non-negative; rel err 2^-8 ok at 5x margin)
__device__ __forceinline__ unsigned pk2t(float lo, float hi) {
    union { float f; unsigned u; } a, b;
    a.f = lo; b.f = hi;
    return __builtin_amdgcn_perm(b.u, a.u, 0x07060302u);
}

// ---- fragment pre-swizzle: F[hd][tile][frag][lane][8] bf16 ----
// frag 0..7  = K A-frags  (kh*4 + mb*2 + hh): lane(n,qd) holds
//              K[key = 64t + 32kh + 8(n>>2) + (n&3) + 4mb][d = 32hh + 8qd .. +8]
// frag 8..15 = V^T A-frags (8 + kh*4 + mb): lane(n,qd) holds
//              V[key = 64t + 32kh + 8qd + j][d = 16mb + n], j = 0..7
__global__ __launch_bounds__(256)
void cvt8(const float* __restrict__ K, const float* __restrict__ V,
          unsigned short* __restrict__ F)
{
    __shared__ float T[64][68];   // V^T fp32: [d][key]

    const int bid = blockIdx.x;            // 512: hd = bid&15 -> XCD bid%8 (matches attn)
    const int hd = bid & 15, tt = bid >> 4;
    const float* Kt = K + ((size_t)hd * S_ + tt * 64) * D_;
    const float* Vt = V + ((size_t)hd * S_ + tt * 64) * D_;
    unsigned short* Ft = F + (size_t)(hd * 32 + tt) * 8192;

    const int t = threadIdx.x;
    const int key = t >> 2, d0 = (t & 3) << 4;

    // ---- V: coalesced read -> transposed LDS ----
    {
        const float* vp = Vt + key * D_ + d0;
        #pragma unroll
        for (int i = 0; i < 4; ++i) {
            float4 v4 = *(const float4*)(vp + 4 * i);
            T[d0 + 4 * i + 0][key] = v4.x;
            T[d0 + 4 * i + 1][key] = v4.y;
            T[d0 + 4 * i + 2][key] = v4.z;
            T[d0 + 4 * i + 3][key] = v4.w;
        }
    }

    // ---- K: coalesced read -> direct frag write ----
    {
        const float* kp = Kt + key * D_ + d0;
        float4 a = *(const float4*)(kp);
        float4 b = *(const float4*)(kp + 4);
        float4 c = *(const float4*)(kp + 8);
        float4 d = *(const float4*)(kp + 12);
        uint4 w0 = make_uint4(pk2(a.x, a.y), pk2(a.z, a.w), pk2(b.x, b.y), pk2(b.z, b.w));
        uint4 w1 = make_uint4(pk2(c.x, c.y), pk2(c.z, c.w), pk2(d.x, d.y), pk2(d.z, d.w));
        const int r5 = key & 31;
        const int kh = key >> 5, mb = (r5 >> 2) & 1;
        const int n = ((r5 >> 3) << 2) | (r5 & 3);       // inverse key->M-row perm
        const int hh = d0 >> 5, qd0 = (d0 >> 3) & 3;
        const int f0 = (kh << 2) | (mb << 1) | hh;
        *(uint4*)(Ft + f0 * 512 + ((qd0 << 4) | n) * 8)       = w0;
        *(uint4*)(Ft + f0 * 512 + (((qd0 + 1) << 4) | n) * 8) = w1;
    }
    __syncthreads();

    // ---- V frag emission: contiguous LDS reads, coalesced 16B writes ----
    #pragma unroll
    for (int s = 0; s < 2; ++s) {
        const int slot = t + s * 256;
        const int fr = slot >> 6, lane = slot & 63;
        const int kh = fr >> 2, mb = fr & 3, n = lane & 15, qd = lane >> 4;
        const float* row = &T[mb * 16 + n][kh * 32 + qd * 8];
        uint4 w = make_uint4(pk2(row[0], row[1]), pk2(row[2], row[3]),
                             pk2(row[4], row[5]), pk2(row[6], row[7]));
        *(uint4*)(Ft + (8 + fr) * 512 + lane * 8) = w;
    }
}

__global__ __launch_bounds__(512, 4)
void attn10(const float* __restrict__ Q, const float* __restrict__ beta,
            const unsigned short* __restrict__ F, float* __restrict__ out)
{
    __shared__ float slab[2][32][72];   // [kh][row][0..63: O, 64: l]

    const int bid = blockIdx.x;
    const int hd = bid & 15;          // head pinned to XCD bid&7 (2 heads/XCD)
    const int sb = bid >> 4;          // 0..31
    const int pr = sb >> 1;           // pair index 0..15 -> q-tiles (pr, 31-pr)
    const int hf = sb & 1;            // 32-row half of each q-tile

    const float* Qh = Q + (size_t)hd * S_ * D_;
    const unsigned short* Fh = F + (size_t)hd * 32 * 8192;

    const int t = threadIdx.x, lane = t & 63;
    const int wv = t >> 6;
    const int kh = wv & 1, par = (wv >> 1) & 1, qh = wv >> 2;
    const int n_l = lane & 15, qd = lane >> 4;

    // fragment offsets (ushort) within one tile's 8192-ushort block
    const int lo = lane * 8;
    int kfo[2][2], vfo[4];
    #pragma unroll
    for (int mb = 0; mb < 2; ++mb)
        #pragma unroll
        for (int hh = 0; hh < 2; ++hh)
            kfo[mb][hh] = ((kh << 2) | (mb << 1) | hh) * 512 + lo;
    #pragma unroll
    for (int mb = 0; mb < 4; ++mb)
        vfo[mb] = (8 + (kh << 2) + mb) * 512 + lo;

    const int kvo = (kh << 5) + (qd << 3);   // lane's key offset within a tile
    const float* bp = beta + kvo;

    for (int p = 0; p < 2; ++p) {
        const int j = p ? (31 - pr) : pr;
        const int nt = j + 1;
        const int q0 = (j << 6) + (hf << 5);       // this block's 32-row slice
        const int qr = q0 + (qh << 4) + n_l;       // this lane's q row

        // ---- Qeff B-fragment from global fp32 Q (one q-row per lane) ----
        bf16x8 qb[2];
        {
            const float wp = (qr > 0) ? 0.7f : 0.0f;
            const float wn = (qr + 1 < S_) ? 0.7f : 0.0f;
            const float* qc = Qh + (size_t)qr * D_;
            const float* qpp = qc - ((qr > 0) ? D_ : 0);
            const float* qnn = qc + ((qr + 1 < S_) ? D_ : 0);
            #pragma unroll
            for (int hh = 0; hh < 2; ++hh) {
                const int d0 = (hh << 5) + (qd << 3);
                float4 c0 = *(const float4*)(qc + d0),  c1 = *(const float4*)(qc + d0 + 4);
                float4 p0 = *(const float4*)(qpp + d0), p1 = *(const float4*)(qpp + d0 + 4);
                float4 n0 = *(const float4*)(qnn + d0), n1 = *(const float4*)(qnn + d0 + 4);
                float e0 = fmaf(wn, n0.x, fmaf(wp, p0.x, c0.x));
                float e1 = fmaf(wn, n0.y, fmaf(wp, p0.y, c0.y));
                float e2 = fmaf(wn, n0.z, fmaf(wp, p0.z, c0.z));
                float e3 = fmaf(wn, n0.w, fmaf(wp, p0.w, c0.w));
                float e4 = fmaf(wn, n1.x, fmaf(wp, p1.x, c1.x));
                float e5 = fmaf(wn, n1.y, fmaf(wp, p1.y, c1.y));
                float e6 = fmaf(wn, n1.z, fmaf(wp, p1.z, c1.z));
                float e7 = fmaf(wn, n1.w, fmaf(wp, p1.w, c1.w));
                union { unsigned u[4]; bf16x8 v; } qu;
                qu.u[0] = pk2(e0, e1); qu.u[1] = pk2(e2, e3);
                qu.u[2] = pk2(e4, e5); qu.u[3] = pk2(e6, e7);
                qb[hh] = qu.v;
            }
        }

        f32x4 o[4];
        float l = 0.0f;
        #pragma unroll
        for (int mb = 0; mb < 4; ++mb) o[mb] = (f32x4){0, 0, 0, 0};

        auto ldk = [&](int tile, bf16x8 (&ka)[2][2]) {
            const unsigned short* fp = Fh + (size_t)tile * 8192;
            ka[0][0] = *(const bf16x8*)(fp + kfo[0][0]);
            ka[0][1] = *(const bf16x8*)(fp + kfo[0][1]);
            ka[1][0] = *(const bf16x8*)(fp + kfo[1][0]);
            ka[1][1] = *(const bf16x8*)(fp + kfo[1][1]);
        };

        auto comp = [&](int tile, bf16x8 (&ka)[2][2]) {
            const unsigned short* fp = Fh + (size_t)tile * 8192;
            // V-frags + beta issued first; consumed after QK+exp2 (latency covered)
            bf16x8 vb0 = *(const bf16x8*)(fp + vfo[0]);
            bf16x8 vb1 = *(const bf16x8*)(fp + vfo[1]);
            bf16x8 vb2 = *(const bf16x8*)(fp + vfo[2]);
            bf16x8 vb3 = *(const bf16x8*)(fp + vfo[3]);
            const float* bq = bp + (tile << 6);
            const float4 b0 = *(const float4*)(bq);
            const float4 b1 = *(const float4*)(bq + 4);

            const f32x4 zz = {0, 0, 0, 0};
            f32x4 a0 = __builtin_amdgcn_mfma_f32_16x16x32_bf16(ka[0][0], qb[0], zz, 0, 0, 0);
            a0 = __builtin_amdgcn_mfma_f32_16x16x32_bf16(ka[0][1], qb[1], a0, 0, 0, 0);
            f32x4 a1 = __builtin_amdgcn_mfma_f32_16x16x32_bf16(ka[1][0], qb[0], zz, 0, 0, 0);
            a1 = __builtin_amdgcn_mfma_f32_16x16x32_bf16(ka[1][1], qb[1], a1, 0, 0, 0);

            const float bt[8] = {b0.x * LOG2E, b0.y * LOG2E, b0.z * LOG2E, b0.w * LOG2E,
                                 b1.x * LOG2E, b1.y * LOG2E, b1.z * LOG2E, b1.w * LOG2E};
            const bool dm = (tile == nt - 1);
            const int kk = (tile << 6) + kvo;

            float pv[8];
            float la = 0.0f;
            #pragma unroll
            for (int jj = 0; jj < 8; ++jj) {
                const int mb = jj >> 2, r = jj & 3;
                float sv = fmaf((mb ? a1[r] : a0[r]), KSC, bt[jj]);
                if (dm) {
                    const int key = kk + jj;
                    if (!((key < qr) || (qr == 0 && key == 0))) sv = -1.0e30f;
                }
                pv[jj] = __builtin_amdgcn_exp2f(sv);
                la += pv[jj];
            }
            l += la;

            union { unsigned u[4]; bf16x8 v; } pf;
            pf.u[0] = pk2t(pv[0], pv[1]);
            pf.u[1] = pk2t(pv[2], pv[3]);
            pf.u[2] = pk2t(pv[4], pv[5]);
            pf.u[3] = pk2t(pv[6], pv[7]);

            o[0] = __builtin_amdgcn_mfma_f32_16x16x32_bf16(vb0, pf.v, o[0], 0, 0, 0);
            o[1] = __builtin_amdgcn_mfma_f32_16x16x32_bf16(vb1, pf.v, o[1], 0, 0, 0);
            o[2] = __builtin_amdgcn_mfma_f32_16x16x32_bf16(vb2, pf.v, o[2], 0, 0, 0);
            o[3] = __builtin_amdgcn_mfma_f32_16x16x32_bf16(vb3, pf.v, o[3], 0, 0, 0);
        };

        // ---- barrier-free K-loop over this wave's parity class, 2 ka buffers ----
        bf16x8 kaA[2][2], kaB[2][2];
        int it = par;
        if (it < nt) {
            ldk(it, kaA);
            if (it + 2 < nt) ldk(it + 2, kaB);
            while (it + 4 < nt) {
                comp(it, kaA);
                ldk(it + 4, kaA);
                comp(it + 2, kaB);
                if (it + 6 < nt) ldk(it + 6, kaB);
                it += 4;
            }
            comp(it, kaA);
            if (it + 2 < nt) comp(it + 2, kaB);
        }

        // ---- epilogue: quad-reduce l, 4-way (kh x par) combine, store ----
        l += __shfl_xor(l, 16);
        l += __shfl_xor(l, 32);
        __syncthreads();   // protects previous pass's final reads
        const int row = (qh << 4) + n_l;
        if (par == 1) {
            #pragma unroll
            for (int mb = 0; mb < 4; ++mb)
                *(float4*)&slab[kh][row][(mb << 4) + (qd << 2)] =
                    make_float4(o[mb][0], o[mb][1], o[mb][2], o[mb][3]);
            if (qd == 0) slab[kh][row][64] = l;
        }
        __syncthreads();
        if (par == 0) {
            #pragma unroll
            for (int mb = 0; mb < 4; ++mb) {
                float4 pv4 = *(float4*)&slab[kh][row][(mb << 4) + (qd << 2)];
                o[mb][0] += pv4.x; o[mb][1] += pv4.y;
                o[mb][2] += pv4.z; o[mb][3] += pv4.w;
            }
            l += slab[kh][row][64];
            if (kh == 1) {   // publish kh1 totals (same wave read-then-write, in order)
                #pragma unroll
                for (int mb = 0; mb < 4; ++mb)
                    *(float4*)&slab[1][row][(mb << 4) + (qd << 2)] =
                        make_float4(o[mb][0], o[mb][1], o[mb][2], o[mb][3]);
                if (qd == 0) slab[1][row][64] = l;
            }
        }
        __syncthreads();
        if (par == 0 && kh == 0) {
            const float inv = 1.0f / (l + slab[1][row][64]);
            float* op = out + ((size_t)hd * S_ + q0 + row) * D_ + (qd << 2);
            #pragma unroll
            for (int mb = 0; mb < 4; ++mb) {
                float4 pv4 = *(float4*)&slab[1][row][(mb << 4) + (qd << 2)];
                *(float4*)(op + (mb << 4)) =
                    make_float4((o[mb][0] + pv4.x) * inv, (o[mb][1] + pv4.y) * inv,
                                (o[mb][2] + pv4.z) * inv, (o[mb][3] + pv4.w) * inv);
            }
        }
    }
}

extern "C" void kernel_launch(void* const* d_in, const int* in_sizes, int n_in,
                              void* d_out, int out_size, void* d_ws, size_t ws_size,
                              hipStream_t stream) {
    const float* Q    = (const float*)d_in[0];
    const float* K    = (const float*)d_in[1];
    const float* V    = (const float*)d_in[2];
    const float* beta = (const float*)d_in[3];
    // d_in[4]: causal mask (deterministic triu) — handled analytically in-kernel.
    float* out = (float*)d_out;

    unsigned short* F = (unsigned short*)d_ws;   // 16 hd x 32 t x 16 frag x 512 = 8 MB

    cvt8<<<dim3(512), 256, 0, stream>>>(K, V, F);
    attn10<<<dim3(512), 512, 0, stream>>>(Q, beta, F, out);
}